// Round 8
// baseline (650.473 us; speedup 1.0000x reference)
//
#include <hip/hip_runtime.h>
#include <hip/hip_bf16.h>

#define NUM_USER 60000
#define NUM_ITEM 40000
#define NN 100000
#define NE 500000
#define DIM 64
#define KF 4
#define SCAN_CHUNK 512
#define NBLK_SCAN ((NN + 1 + SCAN_CHUNK - 1) / SCAN_CHUNK)

typedef __hip_bfloat16 bf16;

// butterfly sums
__device__ __forceinline__ float red16(float v) {
    v += __shfl_xor(v, 1);
    v += __shfl_xor(v, 2);
    v += __shfl_xor(v, 4);
    v += __shfl_xor(v, 8);
    return v;
}
__device__ __forceinline__ float red8(float v) {
    v += __shfl_xor(v, 1);
    v += __shfl_xor(v, 2);
    v += __shfl_xor(v, 4);
    return v;
}

// bf16x2 (packed in uint, low half = element 0) <-> float2
__device__ __forceinline__ float2 bf2f(unsigned v) {
    float2 r;
    r.x = __uint_as_float(v << 16);
    r.y = __uint_as_float(v & 0xffff0000u);
    return r;
}
__device__ __forceinline__ unsigned packbf(float x, float y) {
    unsigned ux = __float_as_uint(x);
    unsigned uy = __float_as_uint(y);
    ux = (ux + 0x7fffu + ((ux >> 16) & 1u)) >> 16;          // RNE to bf16
    uy = (uy + 0x7fffu + ((uy >> 16) & 1u)) & 0xffff0000u;
    return (ux & 0xffffu) | uy;
}

__device__ __forceinline__ float4 softmax4(float4 s) {
    float m = fmaxf(fmaxf(s.x, s.y), fmaxf(s.z, s.w));
    float e0 = expf(s.x - m), e1 = expf(s.y - m), e2 = expf(s.z - m), e3 = expf(s.w - m);
    float inv = 1.0f / (e0 + e1 + e2 + e3);
    return make_float4(e0 * inv, e1 * inv, e2 * inv, e3 * inv);
}

// wave per node: ego(bf16) = concat(user,item); allemb(fp32) = exact input;
// T(bf16) = tanh(l2n16(input))
__global__ void k_init_tanh(const float* __restrict__ user, const float* __restrict__ item,
                            bf16* __restrict__ ego, float* __restrict__ allemb,
                            bf16* __restrict__ T) {
    int node = (blockIdx.x * blockDim.x + threadIdx.x) >> 6;
    int lane = threadIdx.x & 63;
    if (node >= NN) return;
    int i = node * DIM + lane;
    float v = (node < NUM_USER) ? user[i] : item[i - NUM_USER * DIM];
    ego[i] = __float2bfloat16(v);
    allemb[i] = v;
    float ss = red16(v * v);
    T[i] = __float2bfloat16(tanhf(v / fmaxf(sqrtf(ss), 1e-12f)));
}

__global__ void k_count(const int* __restrict__ row0, const int* __restrict__ col0,
                        int* __restrict__ cnt) {
    int e = blockIdx.x * blockDim.x + threadIdx.x;
    if (e >= NE) return;
    atomicAdd(&cnt[row0[e]], 1);
    atomicAdd(&cnt[col0[e]], 1);
}

__global__ void k_dinv(const int* __restrict__ cnt, float* __restrict__ dinv) {
    int i = blockIdx.x * blockDim.x + threadIdx.x;
    if (i >= NN) return;
    int d = cnt[i];
    dinv[i] = (d > 0) ? rsqrtf((float)d) : 0.0f;
}

// --- 3-stage exclusive scan over cnt[NN] -> ptr[NN+1] ---
__global__ void k_scan1(const int* __restrict__ cnt, int* __restrict__ ptr,
                        int* __restrict__ bsum) {
    __shared__ int sm[SCAN_CHUNK];
    int tid = threadIdx.x;
    int idx = blockIdx.x * SCAN_CHUNK + tid;
    int x = (idx < NN) ? cnt[idx] : 0;
    sm[tid] = x;
    __syncthreads();
    for (int off = 1; off < SCAN_CHUNK; off <<= 1) {
        int v = (tid >= off) ? sm[tid - off] : 0;
        __syncthreads();
        sm[tid] += v;
        __syncthreads();
    }
    if (idx <= NN) ptr[idx] = sm[tid] - x;
    if (tid == SCAN_CHUNK - 1) bsum[blockIdx.x] = sm[tid];
}

__global__ void k_scan2(int* __restrict__ bsum, int* __restrict__ offs) {
    __shared__ int sm[256];
    int tid = threadIdx.x;
    int x = (tid < NBLK_SCAN) ? bsum[tid] : 0;
    sm[tid] = x;
    __syncthreads();
    for (int off = 1; off < 256; off <<= 1) {
        int v = (tid >= off) ? sm[tid - off] : 0;
        __syncthreads();
        sm[tid] += v;
        __syncthreads();
    }
    if (tid < NBLK_SCAN) offs[tid] = sm[tid] - x;
}

__global__ void k_scan3(int* __restrict__ ptr, const int* __restrict__ offs) {
    int idx = blockIdx.x * blockDim.x + threadIdx.x;
    if (idx <= NN) ptr[idx] += offs[idx / SCAN_CHUNK];
}

// build CSR. users are nodes [0,NUM_USER) so user-side slots are exactly [0,NE).
// renumbered edge id := user-side slot j1. eitem maps item slot -> edge id.
__global__ void k_fill(const int* __restrict__ row0, const int* __restrict__ col0,
                       int* __restrict__ pos, int* __restrict__ srcadj,
                       int* __restrict__ eitem, int* __restrict__ jpos1) {
    int e = blockIdx.x * blockDim.x + threadIdx.x;
    if (e >= NE) return;
    int r = row0[e], c = col0[e];
    int j1 = atomicAdd(&pos[r], 1);   // user-side slot (< NE): dst=r, src=c
    srcadj[j1] = c;
    jpos1[e] = j1;
    int j0 = atomicAdd(&pos[c], 1);   // item-side slot (>= NE): dst=c, src=r
    srcadj[j0] = r;
    eitem[j0 - NE] = j1;
}

// one pass: permute S into slot order, compute norm per slot, initial weights
__global__ void k_w0(const float* __restrict__ Sin, const int* __restrict__ row0,
                     const int* __restrict__ col0, const int* __restrict__ jpos1,
                     const float* __restrict__ dinv, float4* __restrict__ Scur4,
                     float* __restrict__ normu, float4* __restrict__ w0) {
    int e = blockIdx.x * blockDim.x + threadIdx.x;
    if (e >= NE) return;
    int j = jpos1[e];
    float n = dinv[row0[e]] * dinv[col0[e]];
    float4 s = make_float4(Sin[e], Sin[NE + e], Sin[2 * NE + e], Sin[3 * NE + e]);
    float4 p = softmax4(s);
    Scur4[j] = s;
    normu[j] = n;
    w0[j] = make_float4(n * p.x, n * p.y, n * p.z, n * p.w);
}

// Scur4 (slot order) -> Sout [4][E] original edge order
__global__ void k_sout(const float4* __restrict__ Scur4, const int* __restrict__ jpos1,
                       float* __restrict__ Sout) {
    int e = blockIdx.x * blockDim.x + threadIdx.x;
    if (e >= NE) return;
    float4 s = Scur4[jpos1[e]];
    Sout[e] = s.x;
    Sout[NE + e] = s.y;
    Sout[2 * NE + e] = s.z;
    Sout[3 * NE + e] = s.w;
}

// fused gather conv + routing score. wave per node, bf16x2 lanes:
// lane l in [0,32) owns dims {2l,2l+1}, factor k = l>>3; half h = lane>>5
// processes edges jj+h — two edges per trip, x2 unrolled (4 edges in flight).
// flags: 1 = layer end (allemb += acc), 2 = write Twrite, 4 = write xnext
__global__ __launch_bounds__(256) void k_conv_score(
        const int* __restrict__ ptr, const int* __restrict__ srcadj,
        const int* __restrict__ eitem, const float* __restrict__ wcur,
        float* __restrict__ pscore, const unsigned* __restrict__ ego2,
        const unsigned* __restrict__ T2, unsigned* __restrict__ Tw2,
        unsigned* __restrict__ xn2, float* __restrict__ allemb, int flags) {
    int node = (blockIdx.x * blockDim.x + threadIdx.x) >> 6;
    int lane = threadIdx.x & 63;
    if (node >= NN) return;
    int l = lane & 31;
    int h = lane >> 5;
    int k = l >> 3;
    int beg = ptr[node], end = ptr[node + 1];

    float ax0 = 0.0f, ay0 = 0.0f, ax1 = 0.0f, ay1 = 0.0f;
    if (node < NUM_USER) {
        for (int jj = beg; jj < end; jj += 4) {
            int j0 = jj + h, j1 = jj + 2 + h;
            if (j0 < end) {
                int src = srcadj[j0];
                float w = wcur[4 * j0 + k];
                float2 v = bf2f(ego2[src * 32 + l]);
                ax0 = fmaf(w, v.x, ax0);
                ay0 = fmaf(w, v.y, ay0);
            }
            if (j1 < end) {
                int src = srcadj[j1];
                float w = wcur[4 * j1 + k];
                float2 v = bf2f(ego2[src * 32 + l]);
                ax1 = fmaf(w, v.x, ax1);
                ay1 = fmaf(w, v.y, ay1);
            }
        }
    } else {
        for (int jj = beg; jj < end; jj += 4) {
            int j0 = jj + h, j1 = jj + 2 + h;
            if (j0 < end) {
                int src = srcadj[j0];
                float w = wcur[4 * eitem[j0 - NE] + k];
                float2 v = bf2f(ego2[src * 32 + l]);
                ax0 = fmaf(w, v.x, ax0);
                ay0 = fmaf(w, v.y, ay0);
            }
            if (j1 < end) {
                int src = srcadj[j1];
                float w = wcur[4 * eitem[j1 - NE] + k];
                float2 v = bf2f(ego2[src * 32 + l]);
                ax1 = fmaf(w, v.x, ax1);
                ay1 = fmaf(w, v.y, ay1);
            }
        }
    }
    float accx = ax0 + ax1, accy = ay0 + ay1;
    accx += __shfl_xor(accx, 32);
    accy += __shfl_xor(accy, 32);
    // both halves now hold identical full sums for dims {2l, 2l+1}

    if (flags & 1) {
        if (h == 0) {
            int i2 = node * 32 + l;
            float2* ae = (float2*)&allemb[2 * i2];
            float2 a = *ae;
            a.x += accx; a.y += accy;
            *ae = a;
            if (flags & 4) xn2[i2] = packbf(accx, accy);
            if (flags & 2) {
                float ss = red8(accx * accx + accy * accy);
                float inv = 1.0f / fmaxf(sqrtf(ss), 1e-12f);
                Tw2[i2] = packbf(tanhf(accx * inv), tanhf(accy * inv));
            }
        }
    }

    if (node >= NUM_USER) return;

    // ---- routing score: pscore[4*j+k] = <u, T[c_j]>_16 ----
    float ssu = red8(accx * accx + accy * accy);
    float nrm = fmaxf(sqrtf(ssu), 1e-12f);
    float ux = accx / nrm, uy = accy / nrm;
    bool lead = (l & 7) == 0;
    for (int jj = beg; jj < end; jj += 4) {
        int j0 = jj + h, j1 = jj + 2 + h;
        if (j0 < end) {
            float2 t = bf2f(T2[srcadj[j0] * 32 + l]);
            float p = red8(fmaf(ux, t.x, uy * t.y));
            if (lead) pscore[4 * j0 + k] = p;
        }
        if (j1 < end) {
            float2 t = bf2f(T2[srcadj[j1] * 32 + l]);
            float p = red8(fmaf(ux, t.x, uy * t.y));
            if (lead) pscore[4 * j1 + k] = p;
        }
    }
}

// thread per edge slot, all sequential float4:
// snew = softmax4(S4) + pscore; S4 = snew; if !last: w = normu * softmax4(snew)
__global__ void k_supd(float4* __restrict__ S4, const float4* __restrict__ pscore,
                       const float* __restrict__ normu, float4* __restrict__ w,
                       int last) {
    int j = blockIdx.x * blockDim.x + threadIdx.x;
    if (j >= NE) return;
    float4 s = softmax4(S4[j]);
    float4 p = pscore[j];
    float4 snew = make_float4(s.x + p.x, s.y + p.y, s.z + p.z, s.w + p.w);
    S4[j] = snew;
    if (!last) {
        float4 q = softmax4(snew);
        float n = normu[j];
        w[j] = make_float4(n * q.x, n * q.y, n * q.z, n * q.w);
    }
}

extern "C" void kernel_launch(void* const* d_in, const int* in_sizes, int n_in,
                              void* d_out, int out_size, void* d_ws, size_t ws_size,
                              hipStream_t stream) {
    const float* user = (const float*)d_in[0];
    const float* item = (const float*)d_in[1];
    const float* S_in = (const float*)d_in[2];
    const int* edge = (const int*)d_in[3];
    const int* row0 = edge;
    const int* col0 = edge + NE;

    float* out = (float*)d_out;
    float* allemb = out;              // NN*DIM floats
    float* Sfinal = out + NN * DIM;   // KF*NE floats

    char* ws = (char*)d_ws;
    size_t off = 0;
    auto carve = [&](size_t bytes) { void* p = ws + off; off += (bytes + 255) & ~(size_t)255; return p; };
    int* cnt = (int*)carve((NN + 1) * sizeof(int));
    int* ptr = (int*)carve((NN + 1) * sizeof(int));
    int* pos = (int*)carve((NN + 1) * sizeof(int));
    int* bsum = (int*)carve(256 * sizeof(int));
    int* offs = (int*)carve(256 * sizeof(int));
    int* srcadj = (int*)carve((size_t)2 * NE * sizeof(int));
    int* eitem = (int*)carve((size_t)NE * sizeof(int));
    int* jpos1 = (int*)carve((size_t)NE * sizeof(int));
    float* dinv = (float*)carve(NN * sizeof(float));
    float* normu = (float*)carve((size_t)NE * sizeof(float));
    float4* Scur4 = (float4*)carve((size_t)NE * sizeof(float4));
    float4* wbuf = (float4*)carve((size_t)NE * sizeof(float4));
    float4* pscore = (float4*)carve((size_t)NE * sizeof(float4));
    bf16* egoA = (bf16*)carve((size_t)NN * DIM * sizeof(bf16));
    bf16* egoB = (bf16*)carve((size_t)NN * DIM * sizeof(bf16));
    bf16* TA = (bf16*)carve((size_t)NN * DIM * sizeof(bf16));
    bf16* TB = (bf16*)carve((size_t)NN * DIM * sizeof(bf16));

    hipMemsetAsync(cnt, 0, (NN + 1) * sizeof(int), stream);

    k_count<<<(NE + 255) / 256, 256, 0, stream>>>(row0, col0, cnt);
    k_dinv<<<(NN + 255) / 256, 256, 0, stream>>>(cnt, dinv);
    k_scan1<<<NBLK_SCAN, SCAN_CHUNK, 0, stream>>>(cnt, ptr, bsum);
    k_scan2<<<1, 256, 0, stream>>>(bsum, offs);
    k_scan3<<<(NN + 1 + 255) / 256, 256, 0, stream>>>(ptr, offs);
    hipMemcpyAsync(pos, ptr, (NN + 1) * sizeof(int), hipMemcpyDeviceToDevice, stream);
    k_fill<<<(NE + 255) / 256, 256, 0, stream>>>(row0, col0, pos, srcadj, eitem, jpos1);
    k_w0<<<(NE + 255) / 256, 256, 0, stream>>>(S_in, row0, col0, jpos1, dinv,
                                               Scur4, normu, wbuf);
    k_init_tanh<<<(NN * 64 + 255) / 256, 256, 0, stream>>>(user, item, egoA, allemb, TA);

    bf16* ego = egoA;
    bf16* xn = egoB;
    bf16* Trd = TA;
    bf16* Twr = TB;
    for (int layer = 0; layer < 2; ++layer) {
        for (int it = 0; it < 2; ++it) {
            int flags = 0;
            if (it == 1) flags |= 1;                   // layer end: allemb += acc
            if (it == 1 && layer == 0) flags |= 2 | 4; // write T + next ego
            k_conv_score<<<(NN * 64 + 255) / 256, 256, 0, stream>>>(
                ptr, srcadj, eitem, (const float*)wbuf, (float*)pscore,
                (const unsigned*)ego, (const unsigned*)Trd, (unsigned*)Twr,
                (unsigned*)xn, allemb, flags);
            int last = (layer == 1 && it == 1) ? 1 : 0;
            k_supd<<<(NE + 255) / 256, 256, 0, stream>>>(Scur4, pscore, normu, wbuf, last);
        }
        bf16* t = ego; ego = xn; xn = t;
        t = Trd; Trd = Twr; Twr = t;
    }
    k_sout<<<(NE + 255) / 256, 256, 0, stream>>>(Scur4, jpos1, Sfinal);
}

// Round 9
// 526.617 us; speedup vs baseline: 1.2352x; 1.2352x over previous
//
#include <hip/hip_runtime.h>
#include <hip/hip_bf16.h>

#define NUM_USER 60000
#define NUM_ITEM 40000
#define NN 100000
#define NE 500000
#define DIM 64
#define KF 4
#define SCAN_CHUNK 512
#define NBLK_SCAN ((NN + 1 + SCAN_CHUNK - 1) / SCAN_CHUNK)
// padded slot-count upper bounds (each node rounds up to multiple of 4)
#define NEPU_MAX (NE + 3 * NUM_USER)   // 680000 user-side slots max
#define NEPI_MAX (NE + 3 * NUM_ITEM)   // 620000 item-side slots max

// sum within each 16-lane group (butterfly: all lanes get result)
__device__ __forceinline__ float red16(float v) {
    v += __shfl_xor(v, 1);
    v += __shfl_xor(v, 2);
    v += __shfl_xor(v, 4);
    v += __shfl_xor(v, 8);
    return v;
}

__device__ __forceinline__ float b2f(unsigned short u) {
    return __uint_as_float(((unsigned)u) << 16);
}
__device__ __forceinline__ unsigned short f2b(float x) {
    unsigned u = __float_as_uint(x);
    u = (u + 0x7fffu + ((u >> 16) & 1u)) >> 16;   // RNE
    return (unsigned short)u;
}

__device__ __forceinline__ float4 softmax4(float4 s) {
    float m = fmaxf(fmaxf(s.x, s.y), fmaxf(s.z, s.w));
    float e0 = expf(s.x - m), e1 = expf(s.y - m), e2 = expf(s.z - m), e3 = expf(s.w - m);
    float inv = 1.0f / (e0 + e1 + e2 + e3);
    return make_float4(e0 * inv, e1 * inv, e2 * inv, e3 * inv);
}

// wave per node: ego(bf16) = concat(user,item); allemb(fp32); T(bf16) = tanh(l2n16)
__global__ void k_init_tanh(const float* __restrict__ user, const float* __restrict__ item,
                            unsigned short* __restrict__ ego, float* __restrict__ allemb,
                            unsigned short* __restrict__ T) {
    int node = (blockIdx.x * blockDim.x + threadIdx.x) >> 6;
    int lane = threadIdx.x & 63;
    if (node >= NN) return;
    int i = node * DIM + lane;
    float v = (node < NUM_USER) ? user[i] : item[i - NUM_USER * DIM];
    ego[i] = f2b(v);
    allemb[i] = v;
    float ss = red16(v * v);
    T[i] = f2b(tanhf(v / fmaxf(sqrtf(ss), 1e-12f)));
}

__global__ void k_count(const int* __restrict__ row0, const int* __restrict__ col0,
                        int* __restrict__ cnt) {
    int e = blockIdx.x * blockDim.x + threadIdx.x;
    if (e >= NE) return;
    atomicAdd(&cnt[row0[e]], 1);
    atomicAdd(&cnt[col0[e]], 1);
}

// dinv + padded counts (round degree up to multiple of 4)
__global__ void k_dinv_pad(const int* __restrict__ cnt, float* __restrict__ dinv,
                           int* __restrict__ cntp) {
    int i = blockIdx.x * blockDim.x + threadIdx.x;
    if (i >= NN) return;
    int d = cnt[i];
    dinv[i] = (d > 0) ? rsqrtf((float)d) : 0.0f;
    cntp[i] = (d + 3) & ~3;
}

// --- 3-stage exclusive scan over cntp[NN] -> ptr[NN+1] ---
__global__ void k_scan1(const int* __restrict__ cnt, int* __restrict__ ptr,
                        int* __restrict__ bsum) {
    __shared__ int sm[SCAN_CHUNK];
    int tid = threadIdx.x;
    int idx = blockIdx.x * SCAN_CHUNK + tid;
    int x = (idx < NN) ? cnt[idx] : 0;
    sm[tid] = x;
    __syncthreads();
    for (int off = 1; off < SCAN_CHUNK; off <<= 1) {
        int v = (tid >= off) ? sm[tid - off] : 0;
        __syncthreads();
        sm[tid] += v;
        __syncthreads();
    }
    if (idx <= NN) ptr[idx] = sm[tid] - x;
    if (tid == SCAN_CHUNK - 1) bsum[blockIdx.x] = sm[tid];
}

__global__ void k_scan2(int* __restrict__ bsum, int* __restrict__ offs) {
    __shared__ int sm[256];
    int tid = threadIdx.x;
    int x = (tid < NBLK_SCAN) ? bsum[tid] : 0;
    sm[tid] = x;
    __syncthreads();
    for (int off = 1; off < 256; off <<= 1) {
        int v = (tid >= off) ? sm[tid - off] : 0;
        __syncthreads();
        sm[tid] += v;
        __syncthreads();
    }
    if (tid < NBLK_SCAN) offs[tid] = sm[tid] - x;
}

__global__ void k_scan3(int* __restrict__ ptr, const int* __restrict__ offs) {
    int idx = blockIdx.x * blockDim.x + threadIdx.x;
    if (idx <= NN) ptr[idx] += offs[idx / SCAN_CHUNK];
}

// fill CSR. user-side slots are [0, ptr[NUM_USER]); edge id := user-side slot j1.
__global__ void k_fill(const int* __restrict__ row0, const int* __restrict__ col0,
                       int* __restrict__ pos, const int* __restrict__ ptr,
                       int* __restrict__ srcadj, int* __restrict__ eitem,
                       int* __restrict__ jpos1) {
    int e = blockIdx.x * blockDim.x + threadIdx.x;
    if (e >= NE) return;
    int r = row0[e], c = col0[e];
    int ptrU = ptr[NUM_USER];
    int j1 = atomicAdd(&pos[r], 1);   // user-side slot: dst=r, src=c
    srcadj[j1] = c;
    jpos1[e] = j1;
    int j0 = atomicAdd(&pos[c], 1);   // item-side slot: dst=c, src=r
    srcadj[j0] = r;
    eitem[j0 - ptrU] = j1;
}

// fill dummy (padding) slots: src=0; item dummies point at zeroed sentinel weight
__global__ void k_pad(const int* __restrict__ cnt, const int* __restrict__ ptr,
                      int* __restrict__ srcadj, int* __restrict__ eitem) {
    int n = blockIdx.x * blockDim.x + threadIdx.x;
    if (n >= NN) return;
    int realend = ptr[n] + cnt[n];
    int end = ptr[n + 1];
    int ptrU = ptr[NUM_USER];
    for (int j = realend; j < end; ++j) {
        srcadj[j] = 0;
        if (n >= NUM_USER) eitem[j - ptrU] = NEPU_MAX;   // w[sentinel]=0
    }
}

// permute S into slot order, norm per slot, initial weights (real slots only;
// dummy slots stay 0 from the memsets)
__global__ void k_w0(const float* __restrict__ Sin, const int* __restrict__ row0,
                     const int* __restrict__ col0, const int* __restrict__ jpos1,
                     const float* __restrict__ dinv, float4* __restrict__ Scur4,
                     float* __restrict__ normu, float4* __restrict__ w0) {
    int e = blockIdx.x * blockDim.x + threadIdx.x;
    if (e >= NE) return;
    int j = jpos1[e];
    float n = dinv[row0[e]] * dinv[col0[e]];
    float4 s = make_float4(Sin[e], Sin[NE + e], Sin[2 * NE + e], Sin[3 * NE + e]);
    float4 p = softmax4(s);
    Scur4[j] = s;
    normu[j] = n;
    w0[j] = make_float4(n * p.x, n * p.y, n * p.z, n * p.w);
}

// Scur4 (slot order) -> Sout [4][E] original edge order
__global__ void k_sout(const float4* __restrict__ Scur4, const int* __restrict__ jpos1,
                       float* __restrict__ Sout) {
    int e = blockIdx.x * blockDim.x + threadIdx.x;
    if (e >= NE) return;
    float4 s = Scur4[jpos1[e]];
    Sout[e] = s.x;
    Sout[NE + e] = s.y;
    Sout[2 * NE + e] = s.z;
    Sout[3 * NE + e] = s.w;
}

// fused gather conv + routing score. wave per node; branch-free x4 loops
// (degree padded to multiple of 4). lane = dim, k = lane>>4 = factor.
// flags: 1 = layer end (allemb += acc), 2 = write Twrite, 4 = write xnext
__global__ __launch_bounds__(256) void k_conv_score(
        const int* __restrict__ ptr, const int* __restrict__ srcadj,
        const int* __restrict__ eitem, const float* __restrict__ wcur,
        float* __restrict__ pscore, const unsigned short* __restrict__ ego,
        const unsigned short* __restrict__ Tread, unsigned short* __restrict__ Twrite,
        unsigned short* __restrict__ xnext, float* __restrict__ allemb, int flags) {
    int node = (blockIdx.x * blockDim.x + threadIdx.x) >> 6;
    int lane = threadIdx.x & 63;
    if (node >= NN) return;
    int beg = __builtin_amdgcn_readfirstlane(ptr[node]);
    int end = __builtin_amdgcn_readfirstlane(ptr[node + 1]);
    int k = lane >> 4;

    float a0 = 0.0f, a1 = 0.0f, a2 = 0.0f, a3 = 0.0f;
    if (node < NUM_USER) {
        for (int j = beg; j < end; j += 4) {
            int4 s = *(const int4*)(srcadj + j);
            float w0 = wcur[4 * j + k], w1 = wcur[4 * j + 4 + k];
            float w2 = wcur[4 * j + 8 + k], w3 = wcur[4 * j + 12 + k];
            a0 = fmaf(w0, b2f(ego[s.x * DIM + lane]), a0);
            a1 = fmaf(w1, b2f(ego[s.y * DIM + lane]), a1);
            a2 = fmaf(w2, b2f(ego[s.z * DIM + lane]), a2);
            a3 = fmaf(w3, b2f(ego[s.w * DIM + lane]), a3);
        }
    } else {
        int ptrU = __builtin_amdgcn_readfirstlane(ptr[NUM_USER]);
        for (int j = beg; j < end; j += 4) {
            int4 s = *(const int4*)(srcadj + j);
            int4 e4 = *(const int4*)(eitem + (j - ptrU));
            float w0 = wcur[4 * e4.x + k], w1 = wcur[4 * e4.y + k];
            float w2 = wcur[4 * e4.z + k], w3 = wcur[4 * e4.w + k];
            a0 = fmaf(w0, b2f(ego[s.x * DIM + lane]), a0);
            a1 = fmaf(w1, b2f(ego[s.y * DIM + lane]), a1);
            a2 = fmaf(w2, b2f(ego[s.z * DIM + lane]), a2);
            a3 = fmaf(w3, b2f(ego[s.w * DIM + lane]), a3);
        }
    }
    float acc = (a0 + a1) + (a2 + a3);

    if (flags & 1) {
        int i = node * DIM + lane;
        allemb[i] += acc;
        if (flags & 4) xnext[i] = f2b(acc);
        if (flags & 2) {
            float ss = red16(acc * acc);
            Twrite[i] = f2b(tanhf(acc / fmaxf(sqrtf(ss), 1e-12f)));
        }
    }

    if (node >= NUM_USER) return;

    // routing score: pscore[4*j+k] = <u, T[src_j]>_16 (dummy slots harmless)
    float ssu = red16(acc * acc);
    float u = acc / fmaxf(sqrtf(ssu), 1e-12f);
    bool lead = (lane & 15) == 0;
    for (int j = beg; j < end; j += 4) {
        int4 s = *(const int4*)(srcadj + j);
        float p0 = red16(u * b2f(Tread[s.x * DIM + lane]));
        float p1 = red16(u * b2f(Tread[s.y * DIM + lane]));
        float p2 = red16(u * b2f(Tread[s.z * DIM + lane]));
        float p3 = red16(u * b2f(Tread[s.w * DIM + lane]));
        if (lead) {
            pscore[4 * j + k] = p0;
            pscore[4 * j + 4 + k] = p1;
            pscore[4 * j + 8 + k] = p2;
            pscore[4 * j + 12 + k] = p3;
        }
    }
}

// thread per padded user slot: snew = softmax4(S4)+pscore; S4=snew;
// if !last: w = normu * softmax4(snew)  (dummy slots: normu=0 -> w=0)
__global__ void k_supd(const int* __restrict__ ptr, float4* __restrict__ S4,
                       const float4* __restrict__ pscore, const float* __restrict__ normu,
                       float4* __restrict__ w, int last) {
    int j = blockIdx.x * blockDim.x + threadIdx.x;
    if (j >= ptr[NUM_USER]) return;
    float4 s = softmax4(S4[j]);
    float4 p = pscore[j];
    float4 snew = make_float4(s.x + p.x, s.y + p.y, s.z + p.z, s.w + p.w);
    S4[j] = snew;
    if (!last) {
        float4 q = softmax4(snew);
        float n = normu[j];
        w[j] = make_float4(n * q.x, n * q.y, n * q.z, n * q.w);
    }
}

extern "C" void kernel_launch(void* const* d_in, const int* in_sizes, int n_in,
                              void* d_out, int out_size, void* d_ws, size_t ws_size,
                              hipStream_t stream) {
    const float* user = (const float*)d_in[0];
    const float* item = (const float*)d_in[1];
    const float* S_in = (const float*)d_in[2];
    const int* edge = (const int*)d_in[3];
    const int* row0 = edge;
    const int* col0 = edge + NE;

    float* out = (float*)d_out;
    float* allemb = out;              // NN*DIM floats
    float* Sfinal = out + NN * DIM;   // KF*NE floats

    char* ws = (char*)d_ws;
    size_t off = 0;
    auto carve = [&](size_t bytes) { void* p = ws + off; off += (bytes + 255) & ~(size_t)255; return p; };
    int* cnt = (int*)carve((NN + 1) * sizeof(int));
    int* cntp = (int*)carve((NN + 1) * sizeof(int));
    int* ptr = (int*)carve((NN + 1) * sizeof(int));
    int* pos = (int*)carve((NN + 1) * sizeof(int));
    int* bsum = (int*)carve(256 * sizeof(int));
    int* offs = (int*)carve(256 * sizeof(int));
    int* srcadj = (int*)carve((size_t)(NEPU_MAX + NEPI_MAX) * sizeof(int));
    int* eitem = (int*)carve((size_t)NEPI_MAX * sizeof(int));
    int* jpos1 = (int*)carve((size_t)NE * sizeof(int));
    float* dinv = (float*)carve(NN * sizeof(float));
    float* normu = (float*)carve((size_t)NEPU_MAX * sizeof(float));
    float4* Scur4 = (float4*)carve((size_t)NEPU_MAX * sizeof(float4));
    float4* wbuf = (float4*)carve((size_t)(NEPU_MAX + 1) * sizeof(float4));
    float4* pscore = (float4*)carve((size_t)NEPU_MAX * sizeof(float4));
    unsigned short* egoA = (unsigned short*)carve((size_t)NN * DIM * 2);
    unsigned short* egoB = (unsigned short*)carve((size_t)NN * DIM * 2);
    unsigned short* TA = (unsigned short*)carve((size_t)NN * DIM * 2);
    unsigned short* TB = (unsigned short*)carve((size_t)NN * DIM * 2);

    hipMemsetAsync(cnt, 0, (NN + 1) * sizeof(int), stream);
    hipMemsetAsync(normu, 0, (size_t)NEPU_MAX * sizeof(float), stream);
    hipMemsetAsync(Scur4, 0, (size_t)NEPU_MAX * sizeof(float4), stream);
    hipMemsetAsync(wbuf, 0, (size_t)(NEPU_MAX + 1) * sizeof(float4), stream);

    k_count<<<(NE + 255) / 256, 256, 0, stream>>>(row0, col0, cnt);
    k_dinv_pad<<<(NN + 255) / 256, 256, 0, stream>>>(cnt, dinv, cntp);
    k_scan1<<<NBLK_SCAN, SCAN_CHUNK, 0, stream>>>(cntp, ptr, bsum);
    k_scan2<<<1, 256, 0, stream>>>(bsum, offs);
    k_scan3<<<(NN + 1 + 255) / 256, 256, 0, stream>>>(ptr, offs);
    hipMemcpyAsync(pos, ptr, (NN + 1) * sizeof(int), hipMemcpyDeviceToDevice, stream);
    k_fill<<<(NE + 255) / 256, 256, 0, stream>>>(row0, col0, pos, ptr, srcadj, eitem, jpos1);
    k_pad<<<(NN + 255) / 256, 256, 0, stream>>>(cnt, ptr, srcadj, eitem);
    k_w0<<<(NE + 255) / 256, 256, 0, stream>>>(S_in, row0, col0, jpos1, dinv,
                                               Scur4, normu, wbuf);
    k_init_tanh<<<(NN * 64 + 255) / 256, 256, 0, stream>>>(user, item, egoA, allemb, TA);

    unsigned short* ego = egoA;
    unsigned short* xn = egoB;
    unsigned short* Trd = TA;
    unsigned short* Twr = TB;
    for (int layer = 0; layer < 2; ++layer) {
        for (int it = 0; it < 2; ++it) {
            int flags = 0;
            if (it == 1) flags |= 1;                   // layer end: allemb += acc
            if (it == 1 && layer == 0) flags |= 2 | 4; // write T + next ego
            k_conv_score<<<(NN * 64 + 255) / 256, 256, 0, stream>>>(
                ptr, srcadj, eitem, (const float*)wbuf, (float*)pscore,
                ego, Trd, Twr, xn, allemb, flags);
            int last = (layer == 1 && it == 1) ? 1 : 0;
            k_supd<<<(NEPU_MAX + 255) / 256, 256, 0, stream>>>(
                ptr, Scur4, pscore, normu, wbuf, last);
        }
        unsigned short* t = ego; ego = xn; xn = t;
        t = Trd; Trd = Twr; Twr = t;
    }
    k_sout<<<(NE + 255) / 256, 256, 0, stream>>>(Scur4, jpos1, Sfinal);
}